// Round 1
// baseline (267.960 us; speedup 1.0000x reference)
//
#include <hip/hip_runtime.h>
#include <hip/hip_bf16.h>
#include <stdint.h>

// out[b,l,i,o] = sum_d head[b,i,d]*U[l,d]*dep[b,o,d] + t2h[b,l,i] + t2d[b,l,o] + b[l]
// B=16, S=256, D=768, L=32. out (16,32,256,256) fp32.
//
// R3: fragment-major LDS layouts [kgrp][row][8] (conflict-free ds_read_b128,
// linear DMA from fragment-major depb), double-buffered single-barrier K-loop
// with issue-early/write-late A staging, XCD-bijective block swizzle,
// nontemporal output stores. prep unchanged except depb written fragment-major.

#define B_ 16
#define S_ 256
#define D_ 768
#define L_ 32
#define KQ_ (D_ / 8)  // 96 groups of 8 d's

typedef unsigned short ushort_t;
typedef __attribute__((ext_vector_type(4))) float f32x4;
typedef __attribute__((ext_vector_type(8))) short s16x8;

typedef __attribute__((address_space(1))) const unsigned int guint;
typedef __attribute__((address_space(3))) unsigned int luint;

__device__ __forceinline__ void async_load16(const ushort_t* g, ushort_t* l) {
  __builtin_amdgcn_global_load_lds((guint*)g, (luint*)l, 16, 0, 0);
}

// round-half-up fp32->bf16 pair pack; f0 -> low half, f1 -> high half
__device__ __forceinline__ unsigned int pack_bf16(float f0, float f1) {
  unsigned int u0 = __builtin_bit_cast(unsigned int, f0) + 0x8000u;
  unsigned int u1 = __builtin_bit_cast(unsigned int, f1) + 0x8000u;
  return __builtin_amdgcn_perm(u1, u0, 0x07060302);
}

// ---------------------------------------------------------------------------
// Prep: one wave per 4 rows. Lane owns 12 d's in registers. t2 dots via
// per-lane FMA + butterfly shuffle reduce. dep waves also emit bf16 depb in
// fragment-major layout depb[b][d>>3][col][d&7].
// grid = 512 blocks x 256 thr = 2048 waves = B*S*2/4 rows.
// ---------------------------------------------------------------------------
__global__ __launch_bounds__(256) void prep_kernel(
    const float* __restrict__ head, const float* __restrict__ dep,
    const float* __restrict__ labelW, ushort_t* __restrict__ depb,
    float* __restrict__ t2h, float* __restrict__ t2d) {
  const int wave = threadIdx.x >> 6;
  const int lane = threadIdx.x & 63;
  const int g = blockIdx.x * 4 + wave;  // 0..2047
  const int sel = g >> 10;              // 0=head, 1=dep
  const int idx = g & 1023;
  const int b = idx >> 6;
  const int row0 = (idx & 63) * 4;
  const float* src = sel ? dep : head;
  float* t2x = sel ? t2d : t2h;
  const int d0 = lane * 12;

  float h[4][12];
  const float* rp = src + ((size_t)(b * S_ + row0)) * D_ + d0;
#pragma unroll
  for (int r = 0; r < 4; ++r) {
    float4 v0 = *(const float4*)(rp + (size_t)r * D_);
    float4 v1 = *(const float4*)(rp + (size_t)r * D_ + 4);
    float4 v2 = *(const float4*)(rp + (size_t)r * D_ + 8);
    h[r][0] = v0.x; h[r][1] = v0.y; h[r][2] = v0.z; h[r][3] = v0.w;
    h[r][4] = v1.x; h[r][5] = v1.y; h[r][6] = v1.z; h[r][7] = v1.w;
    h[r][8] = v2.x; h[r][9] = v2.y; h[r][10] = v2.z; h[r][11] = v2.w;
  }
  if (sel) {
    // fragment-major: ushort off = ((b*96 + (d>>3))*256 + col)*8 + (d&7)
    const size_t bb = (size_t)b * (KQ_ * S_ * 8);
    const int m = lane >> 1;  // d0 = 24m (even lane) or 24m+12 (odd lane)
#pragma unroll
    for (int r = 0; r < 4; ++r) {
      const int col = row0 + r;
      unsigned int q0 = pack_bf16(h[r][0], h[r][1]);
      unsigned int q1 = pack_bf16(h[r][2], h[r][3]);
      unsigned int q2 = pack_bf16(h[r][4], h[r][5]);
      unsigned int q3 = pack_bf16(h[r][6], h[r][7]);
      unsigned int q4 = pack_bf16(h[r][8], h[r][9]);
      unsigned int q5 = pack_bf16(h[r][10], h[r][11]);
      if ((lane & 1) == 0) {
        uint4 a = {q0, q1, q2, q3};  // d0..d7 @ kq=3m
        uint2 c = {q4, q5};          // d8..d11 @ kq=3m+1, dlow 0..3
        *(uint4*)(depb + bb + ((size_t)(3 * m) * S_ + col) * 8) = a;
        *(uint2*)(depb + bb + ((size_t)(3 * m + 1) * S_ + col) * 8) = c;
      } else {
        uint2 c = {q0, q1};          // d0..d3 @ kq=3m+1, dlow 4..7
        uint4 a = {q2, q3, q4, q5};  // d4..d11 @ kq=3m+2
        *(uint2*)(depb + bb + ((size_t)(3 * m + 1) * S_ + col) * 8 + 4) = c;
        *(uint4*)(depb + bb + ((size_t)(3 * m + 2) * S_ + col) * 8) = a;
      }
    }
  }
  const float* wbase = labelW + sel * D_ + d0;
  for (int l = 0; l < L_; ++l) {
    const float* wp = wbase + (size_t)l * (2 * D_);
    float4 w0 = *(const float4*)(wp);
    float4 w1 = *(const float4*)(wp + 4);
    float4 w2 = *(const float4*)(wp + 8);
    float w[12] = {w0.x, w0.y, w0.z, w0.w, w1.x, w1.y, w1.z, w1.w,
                   w2.x, w2.y, w2.z, w2.w};
    float p0 = 0.f, p1 = 0.f, p2 = 0.f, p3 = 0.f;
#pragma unroll
    for (int j = 0; j < 12; ++j) {
      p0 += h[0][j] * w[j];
      p1 += h[1][j] * w[j];
      p2 += h[2][j] * w[j];
      p3 += h[3][j] * w[j];
    }
#pragma unroll
    for (int off = 32; off >= 1; off >>= 1) {
      p0 += __shfl_xor(p0, off);
      p1 += __shfl_xor(p1, off);
      p2 += __shfl_xor(p2, off);
      p3 += __shfl_xor(p3, off);
    }
    if (lane < 4) {
      float v = lane == 0 ? p0 : lane == 1 ? p1 : lane == 2 ? p2 : p3;
      t2x[((size_t)(b * L_ + l)) * S_ + row0 + lane] = v;
    }
  }
}

// ---------------------------------------------------------------------------
// Main: block = (b, l, i-half). Tile 128(i) x 256(o), 4 waves of 64x128.
// grid = B*L*2 = 1024 blocks, 256 threads. Double-buffered LDS, one barrier
// per 32-wide K-step.
// ---------------------------------------------------------------------------
__global__ __launch_bounds__(256, 2) void main_kernel(
    const float* __restrict__ head, const ushort_t* __restrict__ depb,
    const float* __restrict__ U, const float* __restrict__ bias,
    const float* __restrict__ t2h, const float* __restrict__ t2d,
    float* __restrict__ out) {
  // fragment-major: [buf][kgrp(4)][row][8] bf16
  __shared__ __attribute__((aligned(16))) ushort_t As[2 * 128 * 32];  // 16 KB
  __shared__ __attribute__((aligned(16))) ushort_t Bs[2 * 256 * 32];  // 32 KB
  __shared__ float T2[384];  // [0:128]=t2h tile rows, [128:384]=t2d all cols

  // XCD-bijective swizzle: grid 1024 = 8 XCDs x 128 contiguous blocks (2 b's)
  const int hw = blockIdx.x;
  const int bid = ((hw & 7) << 7) | (hw >> 3);
  const int ic = bid & 1;
  const int bl = bid >> 1;
  const int l = bl & (L_ - 1);
  const int b = bl >> 5;
  const int ti = ic * 128;
  const int t = threadIdx.x;
  const int lane = t & 63;
  const int wave = t >> 6;
  const int m_base = (wave >> 1) * 64;
  const int n_base = (wave & 1) * 128;

  for (int i = t; i < 384; i += 256)
    T2[i] = (i < 128) ? t2h[((size_t)(b * L_ + l)) * S_ + ti + i]
                      : t2d[((size_t)(b * L_ + l)) * S_ + (i - 128)];
  const float bv = bias[l];

  // staging: thread t stages A rows (t>>2, t>>2+64) for kgrp = t&3
  const int row0 = t >> 2;
  const int kg = t & 3;
  const float* hp0 = head + ((size_t)(b * S_ + ti + row0)) * D_ + kg * 8;
  const float* hp1 = hp0 + (size_t)64 * D_;
  const float* Up = U + (size_t)l * D_ + kg * 8;
  const ushort_t* dpb = depb + (size_t)b * (KQ_ * S_ * 8);
  const int awo0 = (kg * 128 + row0) * 8;
  const int awo1 = awo0 + 64 * 8;
  const int dmo = t * 8;  // per-thread 16 B slot within a DMA round

  f32x4 acc[4][8];
#pragma unroll
  for (int i = 0; i < 4; ++i)
#pragma unroll
    for (int j = 0; j < 8; ++j) acc[i][j] = {0.f, 0.f, 0.f, 0.f};

  // frag read offsets (ushorts): sequential 16B per 16-lane group -> no
  // bank conflicts
  const int aro = ((lane >> 4) * 128 + m_base + (lane & 15)) * 8;
  const int bro = ((lane >> 4) * 256 + n_base + (lane & 15)) * 8;

#define DMA_B(BUF, KK)                                                       \
  {                                                                          \
    ushort_t* bw = Bs + (BUF) * 8192;                                        \
    const ushort_t* gs = dpb + (size_t)(KK) * 256;                           \
    async_load16(gs + dmo, bw + dmo);                                        \
    async_load16(gs + 2048 + dmo, bw + 2048 + dmo);                          \
    async_load16(gs + 4096 + dmo, bw + 4096 + dmo);                          \
    async_load16(gs + 6144 + dmo, bw + 6144 + dmo);                          \
  }

#define PACK_WRITE_A(BUF)                                                    \
  {                                                                          \
    uint4 w0, w1;                                                            \
    w0.x = pack_bf16(h0.x * u0.x, h0.y * u0.y);                              \
    w0.y = pack_bf16(h0.z * u0.z, h0.w * u0.w);                              \
    w0.z = pack_bf16(h1.x * u1.x, h1.y * u1.y);                              \
    w0.w = pack_bf16(h1.z * u1.z, h1.w * u1.w);                              \
    w1.x = pack_bf16(h2.x * u0.x, h2.y * u0.y);                              \
    w1.y = pack_bf16(h2.z * u0.z, h2.w * u0.w);                              \
    w1.z = pack_bf16(h3.x * u1.x, h3.y * u1.y);                              \
    w1.w = pack_bf16(h3.z * u1.z, h3.w * u1.w);                              \
    ushort_t* aw = As + (BUF) * 4096;                                        \
    *(uint4*)(aw + awo0) = w0;                                               \
    *(uint4*)(aw + awo1) = w1;                                               \
  }

#define COMPUTE(CUR)                                                         \
  {                                                                          \
    const ushort_t* ar = As + (CUR) * 4096 + aro;                            \
    const ushort_t* br = Bs + (CUR) * 8192 + bro;                            \
    s16x8 af[4], bf[8];                                                      \
    _Pragma("unroll") for (int rt = 0; rt < 4; ++rt)                         \
        af[rt] = *(const s16x8*)(ar + rt * 128);                             \
    _Pragma("unroll") for (int ct = 0; ct < 8; ++ct)                         \
        bf[ct] = *(const s16x8*)(br + ct * 128);                             \
    _Pragma("unroll") for (int rt = 0; rt < 4; ++rt)                         \
      _Pragma("unroll") for (int ct = 0; ct < 8; ++ct)                       \
          acc[rt][ct] = __builtin_amdgcn_mfma_f32_16x16x32_bf16(             \
              af[rt], bf[ct], acc[rt][ct], 0, 0, 0);                         \
  }

  // prologue: fully stage K-tile 0 into buf 0
  {
    DMA_B(0, 0);
    float4 h0 = *(const float4*)(hp0);
    float4 h1 = *(const float4*)(hp0 + 4);
    float4 h2 = *(const float4*)(hp1);
    float4 h3 = *(const float4*)(hp1 + 4);
    float4 u0 = *(const float4*)(Up);
    float4 u1 = *(const float4*)(Up + 4);
    PACK_WRITE_A(0);
  }
  __syncthreads();  // implicit vmcnt(0)+lgkmcnt(0): tile 0 resident

  int cur = 0;
  for (int kk = 0; kk < D_ - 32; kk += 32) {
    // issue next tile early: DMA B + global loads for A (latency hides under
    // the MFMA cluster below)
    DMA_B(cur ^ 1, kk + 32);
    float4 h0 = *(const float4*)(hp0 + kk + 32);
    float4 h1 = *(const float4*)(hp0 + kk + 36);
    float4 h2 = *(const float4*)(hp1 + kk + 32);
    float4 h3 = *(const float4*)(hp1 + kk + 36);
    float4 u0 = *(const float4*)(Up + kk + 32);
    float4 u1 = *(const float4*)(Up + kk + 36);

    COMPUTE(cur);      // current tile: 12 conflict-free ds_read_b128 + 32 MFMA

    PACK_WRITE_A(cur ^ 1);  // write-late: after frag reads, before barrier
    __syncthreads();        // drains DMA (vmcnt) + A writes (lgkm)
    cur ^= 1;
  }
  COMPUTE(cur);  // last K-tile

#undef DMA_B
#undef PACK_WRITE_A
#undef COMPUTE

  // epilogue: C/D layout col=lane&15, row=(lane>>4)*4+reg; nontemporal stores
  // keep the 128 MB stream out of L2 so head/depb stay resident
  const int colg = lane & 15;
  const int rgrp = lane >> 4;
  float* ob = out + (((size_t)(b * L_ + l)) * S_ + ti) * S_;
#pragma unroll
  for (int rt = 0; rt < 4; ++rt) {
    const int r0 = m_base + rt * 16 + rgrp * 4;
#pragma unroll
    for (int ct = 0; ct < 8; ++ct) {
      const int c = n_base + ct * 16 + colg;
      const float addc = T2[128 + c] + bv;
      float* p = ob + (size_t)r0 * S_ + c;
#pragma unroll
      for (int r = 0; r < 4; ++r)
        __builtin_nontemporal_store(acc[rt][ct][r] + T2[r0 + r] + addc,
                                    p + (size_t)r * S_);
    }
  }
}

extern "C" void kernel_launch(void* const* d_in, const int* in_sizes, int n_in,
                              void* d_out, int out_size, void* d_ws, size_t ws_size,
                              hipStream_t stream) {
  const float* head = (const float*)d_in[0];
  const float* dep = (const float*)d_in[1];
  const float* U = (const float*)d_in[2];
  const float* W = (const float*)d_in[3];
  const float* bias = (const float*)d_in[4];
  float* out = (float*)d_out;

  ushort_t* depb = (ushort_t*)d_ws;                              // 6,291,456 B
  float* t2h = (float*)((char*)d_ws + (size_t)B_ * S_ * D_ * 2);
  float* t2d = t2h + (size_t)B_ * L_ * S_;                       // 524,288 B each

  prep_kernel<<<512, 256, 0, stream>>>(head, dep, W, depb, t2h, t2d);
  main_kernel<<<B_ * L_ * 2, 256, 0, stream>>>(head, depb, U, bias, t2h, t2d, out);
}

// Round 2
// 243.664 us; speedup vs baseline: 1.0997x; 1.0997x over previous
//
#include <hip/hip_runtime.h>
#include <hip/hip_bf16.h>
#include <stdint.h>

// out[b,l,i,o] = sum_d head[b,i,d]*U[l,d]*dep[b,o,d] + t2h[b,l,i] + t2d[b,l,o] + b[l]
// B=16, S=256, D=768, L=32. out (16,32,256,256) fp32.
//
// R4: R3 structure (fragment-major LDS, double-buffered single-barrier K-loop,
// issue-early prefetch, XCD swizzle) with: normal stores (nt stores cost
// +50MB HBM writes in R3), sched_barrier(0) pinning the prefetch issue
// cluster above COMPUTE, s_setprio(1) around the MFMA cluster (cross-block
// wave diversity at 2 blocks/CU).

#define B_ 16
#define S_ 256
#define D_ 768
#define L_ 32
#define KQ_ (D_ / 8)  // 96 groups of 8 d's

typedef unsigned short ushort_t;
typedef __attribute__((ext_vector_type(4))) float f32x4;
typedef __attribute__((ext_vector_type(8))) short s16x8;

typedef __attribute__((address_space(1))) const unsigned int guint;
typedef __attribute__((address_space(3))) unsigned int luint;

__device__ __forceinline__ void async_load16(const ushort_t* g, ushort_t* l) {
  __builtin_amdgcn_global_load_lds((guint*)g, (luint*)l, 16, 0, 0);
}

// round-half-up fp32->bf16 pair pack; f0 -> low half, f1 -> high half
__device__ __forceinline__ unsigned int pack_bf16(float f0, float f1) {
  unsigned int u0 = __builtin_bit_cast(unsigned int, f0) + 0x8000u;
  unsigned int u1 = __builtin_bit_cast(unsigned int, f1) + 0x8000u;
  return __builtin_amdgcn_perm(u1, u0, 0x07060302);
}

// ---------------------------------------------------------------------------
// Prep: one wave per 4 rows. Lane owns 12 d's in registers. t2 dots via
// per-lane FMA + butterfly shuffle reduce. dep waves also emit bf16 depb in
// fragment-major layout depb[b][d>>3][col][d&7].
// grid = 512 blocks x 256 thr = 2048 waves = B*S*2/4 rows.
// ---------------------------------------------------------------------------
__global__ __launch_bounds__(256) void prep_kernel(
    const float* __restrict__ head, const float* __restrict__ dep,
    const float* __restrict__ labelW, ushort_t* __restrict__ depb,
    float* __restrict__ t2h, float* __restrict__ t2d) {
  const int wave = threadIdx.x >> 6;
  const int lane = threadIdx.x & 63;
  const int g = blockIdx.x * 4 + wave;  // 0..2047
  const int sel = g >> 10;              // 0=head, 1=dep
  const int idx = g & 1023;
  const int b = idx >> 6;
  const int row0 = (idx & 63) * 4;
  const float* src = sel ? dep : head;
  float* t2x = sel ? t2d : t2h;
  const int d0 = lane * 12;

  float h[4][12];
  const float* rp = src + ((size_t)(b * S_ + row0)) * D_ + d0;
#pragma unroll
  for (int r = 0; r < 4; ++r) {
    float4 v0 = *(const float4*)(rp + (size_t)r * D_);
    float4 v1 = *(const float4*)(rp + (size_t)r * D_ + 4);
    float4 v2 = *(const float4*)(rp + (size_t)r * D_ + 8);
    h[r][0] = v0.x; h[r][1] = v0.y; h[r][2] = v0.z; h[r][3] = v0.w;
    h[r][4] = v1.x; h[r][5] = v1.y; h[r][6] = v1.z; h[r][7] = v1.w;
    h[r][8] = v2.x; h[r][9] = v2.y; h[r][10] = v2.z; h[r][11] = v2.w;
  }
  if (sel) {
    // fragment-major: ushort off = ((b*96 + (d>>3))*256 + col)*8 + (d&7)
    const size_t bb = (size_t)b * (KQ_ * S_ * 8);
    const int m = lane >> 1;  // d0 = 24m (even lane) or 24m+12 (odd lane)
#pragma unroll
    for (int r = 0; r < 4; ++r) {
      const int col = row0 + r;
      unsigned int q0 = pack_bf16(h[r][0], h[r][1]);
      unsigned int q1 = pack_bf16(h[r][2], h[r][3]);
      unsigned int q2 = pack_bf16(h[r][4], h[r][5]);
      unsigned int q3 = pack_bf16(h[r][6], h[r][7]);
      unsigned int q4 = pack_bf16(h[r][8], h[r][9]);
      unsigned int q5 = pack_bf16(h[r][10], h[r][11]);
      if ((lane & 1) == 0) {
        uint4 a = {q0, q1, q2, q3};  // d0..d7 @ kq=3m
        uint2 c = {q4, q5};          // d8..d11 @ kq=3m+1, dlow 0..3
        *(uint4*)(depb + bb + ((size_t)(3 * m) * S_ + col) * 8) = a;
        *(uint2*)(depb + bb + ((size_t)(3 * m + 1) * S_ + col) * 8) = c;
      } else {
        uint2 c = {q0, q1};          // d0..d3 @ kq=3m+1, dlow 4..7
        uint4 a = {q2, q3, q4, q5};  // d4..d11 @ kq=3m+2
        *(uint2*)(depb + bb + ((size_t)(3 * m + 1) * S_ + col) * 8 + 4) = c;
        *(uint4*)(depb + bb + ((size_t)(3 * m + 2) * S_ + col) * 8) = a;
      }
    }
  }
  const float* wbase = labelW + sel * D_ + d0;
  for (int l = 0; l < L_; ++l) {
    const float* wp = wbase + (size_t)l * (2 * D_);
    float4 w0 = *(const float4*)(wp);
    float4 w1 = *(const float4*)(wp + 4);
    float4 w2 = *(const float4*)(wp + 8);
    float w[12] = {w0.x, w0.y, w0.z, w0.w, w1.x, w1.y, w1.z, w1.w,
                   w2.x, w2.y, w2.z, w2.w};
    float p0 = 0.f, p1 = 0.f, p2 = 0.f, p3 = 0.f;
#pragma unroll
    for (int j = 0; j < 12; ++j) {
      p0 += h[0][j] * w[j];
      p1 += h[1][j] * w[j];
      p2 += h[2][j] * w[j];
      p3 += h[3][j] * w[j];
    }
#pragma unroll
    for (int off = 32; off >= 1; off >>= 1) {
      p0 += __shfl_xor(p0, off);
      p1 += __shfl_xor(p1, off);
      p2 += __shfl_xor(p2, off);
      p3 += __shfl_xor(p3, off);
    }
    if (lane < 4) {
      float v = lane == 0 ? p0 : lane == 1 ? p1 : lane == 2 ? p2 : p3;
      t2x[((size_t)(b * L_ + l)) * S_ + row0 + lane] = v;
    }
  }
}

// ---------------------------------------------------------------------------
// Main: block = (b, l, i-half). Tile 128(i) x 256(o), 4 waves of 64x128.
// grid = B*L*2 = 1024 blocks, 256 threads. Double-buffered LDS, one barrier
// per 32-wide K-step.
// ---------------------------------------------------------------------------
__global__ __launch_bounds__(256, 2) void main_kernel(
    const float* __restrict__ head, const ushort_t* __restrict__ depb,
    const float* __restrict__ U, const float* __restrict__ bias,
    const float* __restrict__ t2h, const float* __restrict__ t2d,
    float* __restrict__ out) {
  // fragment-major: [buf][kgrp(4)][row][8] bf16
  __shared__ __attribute__((aligned(16))) ushort_t As[2 * 128 * 32];  // 16 KB
  __shared__ __attribute__((aligned(16))) ushort_t Bs[2 * 256 * 32];  // 32 KB
  __shared__ float T2[384];  // [0:128]=t2h tile rows, [128:384]=t2d all cols

  // XCD-bijective swizzle: grid 1024 = 8 XCDs x 128 contiguous blocks (2 b's)
  const int hw = blockIdx.x;
  const int bid = ((hw & 7) << 7) | (hw >> 3);
  const int ic = bid & 1;
  const int bl = bid >> 1;
  const int l = bl & (L_ - 1);
  const int b = bl >> 5;
  const int ti = ic * 128;
  const int t = threadIdx.x;
  const int lane = t & 63;
  const int wave = t >> 6;
  const int m_base = (wave >> 1) * 64;
  const int n_base = (wave & 1) * 128;

  for (int i = t; i < 384; i += 256)
    T2[i] = (i < 128) ? t2h[((size_t)(b * L_ + l)) * S_ + ti + i]
                      : t2d[((size_t)(b * L_ + l)) * S_ + (i - 128)];
  const float bv = bias[l];

  // staging: thread t stages A rows (t>>2, t>>2+64) for kgrp = t&3
  const int row0 = t >> 2;
  const int kg = t & 3;
  const float* hp0 = head + ((size_t)(b * S_ + ti + row0)) * D_ + kg * 8;
  const float* hp1 = hp0 + (size_t)64 * D_;
  const float* Up = U + (size_t)l * D_ + kg * 8;
  const ushort_t* dpb = depb + (size_t)b * (KQ_ * S_ * 8);
  const int awo0 = (kg * 128 + row0) * 8;
  const int awo1 = awo0 + 64 * 8;
  const int dmo = t * 8;  // per-thread 16 B slot within a DMA round

  f32x4 acc[4][8];
#pragma unroll
  for (int i = 0; i < 4; ++i)
#pragma unroll
    for (int j = 0; j < 8; ++j) acc[i][j] = {0.f, 0.f, 0.f, 0.f};

  // frag read offsets (ushorts): sequential 16B per 16-lane group
  const int aro = ((lane >> 4) * 128 + m_base + (lane & 15)) * 8;
  const int bro = ((lane >> 4) * 256 + n_base + (lane & 15)) * 8;

#define DMA_B(BUF, KK)                                                       \
  {                                                                          \
    ushort_t* bw = Bs + (BUF) * 8192;                                        \
    const ushort_t* gs = dpb + (size_t)(KK) * 256;                           \
    async_load16(gs + dmo, bw + dmo);                                        \
    async_load16(gs + 2048 + dmo, bw + 2048 + dmo);                          \
    async_load16(gs + 4096 + dmo, bw + 4096 + dmo);                          \
    async_load16(gs + 6144 + dmo, bw + 6144 + dmo);                          \
  }

#define PACK_WRITE_A(BUF)                                                    \
  {                                                                          \
    uint4 w0, w1;                                                            \
    w0.x = pack_bf16(h0.x * u0.x, h0.y * u0.y);                              \
    w0.y = pack_bf16(h0.z * u0.z, h0.w * u0.w);                              \
    w0.z = pack_bf16(h1.x * u1.x, h1.y * u1.y);                              \
    w0.w = pack_bf16(h1.z * u1.z, h1.w * u1.w);                              \
    w1.x = pack_bf16(h2.x * u0.x, h2.y * u0.y);                              \
    w1.y = pack_bf16(h2.z * u0.z, h2.w * u0.w);                              \
    w1.z = pack_bf16(h3.x * u1.x, h3.y * u1.y);                              \
    w1.w = pack_bf16(h3.z * u1.z, h3.w * u1.w);                              \
    ushort_t* aw = As + (BUF) * 4096;                                        \
    *(uint4*)(aw + awo0) = w0;                                               \
    *(uint4*)(aw + awo1) = w1;                                               \
  }

#define COMPUTE(CUR)                                                         \
  {                                                                          \
    const ushort_t* ar = As + (CUR) * 4096 + aro;                            \
    const ushort_t* br = Bs + (CUR) * 8192 + bro;                            \
    s16x8 af[4], bf[8];                                                      \
    _Pragma("unroll") for (int rt = 0; rt < 4; ++rt)                         \
        af[rt] = *(const s16x8*)(ar + rt * 128);                             \
    _Pragma("unroll") for (int ct = 0; ct < 8; ++ct)                         \
        bf[ct] = *(const s16x8*)(br + ct * 128);                             \
    __builtin_amdgcn_s_setprio(1);                                           \
    _Pragma("unroll") for (int rt = 0; rt < 4; ++rt)                         \
      _Pragma("unroll") for (int ct = 0; ct < 8; ++ct)                       \
          acc[rt][ct] = __builtin_amdgcn_mfma_f32_16x16x32_bf16(             \
              af[rt], bf[ct], acc[rt][ct], 0, 0, 0);                         \
    __builtin_amdgcn_s_setprio(0);                                           \
  }

  // prologue: fully stage K-tile 0 into buf 0
  {
    DMA_B(0, 0);
    float4 h0 = *(const float4*)(hp0);
    float4 h1 = *(const float4*)(hp0 + 4);
    float4 h2 = *(const float4*)(hp1);
    float4 h3 = *(const float4*)(hp1 + 4);
    float4 u0 = *(const float4*)(Up);
    float4 u1 = *(const float4*)(Up + 4);
    PACK_WRITE_A(0);
  }
  __syncthreads();  // implicit vmcnt(0)+lgkmcnt(0): tile 0 resident

  int cur = 0;
  for (int kk = 0; kk < D_ - 32; kk += 32) {
    // issue next tile early: DMA B + global loads for A (latency hides under
    // the MFMA cluster below). sched_barrier(0) pins this cluster here so the
    // scheduler cannot sink the loads down to their use site after COMPUTE.
    DMA_B(cur ^ 1, kk + 32);
    float4 h0 = *(const float4*)(hp0 + kk + 32);
    float4 h1 = *(const float4*)(hp0 + kk + 36);
    float4 h2 = *(const float4*)(hp1 + kk + 32);
    float4 h3 = *(const float4*)(hp1 + kk + 36);
    float4 u0 = *(const float4*)(Up + kk + 32);
    float4 u1 = *(const float4*)(Up + kk + 36);
    __builtin_amdgcn_sched_barrier(0);

    COMPUTE(cur);      // current tile: 12 ds_read_b128 + 32 MFMA

    PACK_WRITE_A(cur ^ 1);  // write-late: after frag reads, before barrier
    __syncthreads();        // drains DMA (vmcnt) + A writes (lgkm)
    cur ^= 1;
  }
  COMPUTE(cur);  // last K-tile

#undef DMA_B
#undef PACK_WRITE_A
#undef COMPUTE

  // epilogue: C/D layout col=lane&15, row=(lane>>4)*4+reg; normal stores so
  // L2 write-combines the 64B half-lines into full writeback lines
  const int colg = lane & 15;
  const int rgrp = lane >> 4;
  float* ob = out + (((size_t)(b * L_ + l)) * S_ + ti) * S_;
#pragma unroll
  for (int rt = 0; rt < 4; ++rt) {
    const int r0 = m_base + rt * 16 + rgrp * 4;
#pragma unroll
    for (int ct = 0; ct < 8; ++ct) {
      const int c = n_base + ct * 16 + colg;
      const float addc = T2[128 + c] + bv;
      float* p = ob + (size_t)r0 * S_ + c;
#pragma unroll
      for (int r = 0; r < 4; ++r)
        p[(size_t)r * S_] = acc[rt][ct][r] + T2[r0 + r] + addc;
    }
  }
}

extern "C" void kernel_launch(void* const* d_in, const int* in_sizes, int n_in,
                              void* d_out, int out_size, void* d_ws, size_t ws_size,
                              hipStream_t stream) {
  const float* head = (const float*)d_in[0];
  const float* dep = (const float*)d_in[1];
  const float* U = (const float*)d_in[2];
  const float* W = (const float*)d_in[3];
  const float* bias = (const float*)d_in[4];
  float* out = (float*)d_out;

  ushort_t* depb = (ushort_t*)d_ws;                              // 6,291,456 B
  float* t2h = (float*)((char*)d_ws + (size_t)B_ * S_ * D_ * 2);
  float* t2d = t2h + (size_t)B_ * L_ * S_;                       // 524,288 B each

  prep_kernel<<<512, 256, 0, stream>>>(head, dep, W, depb, t2h, t2d);
  main_kernel<<<B_ * L_ * 2, 256, 0, stream>>>(head, depb, U, bias, t2h, t2d, out);
}

// Round 3
// 229.492 us; speedup vs baseline: 1.1676x; 1.0618x over previous
//
#include <hip/hip_runtime.h>
#include <hip/hip_bf16.h>
#include <stdint.h>

// out[b,l,i,o] = sum_d head[b,i,d]*U[l,d]*dep[b,o,d] + t2h[b,l,i] + t2d[b,l,o] + b[l]
// B=16, S=256, D=768, L=32. out (16,32,256,256) fp32.
//
// R5: no global_load_lds, no vmcnt drain anywhere in the K-loop.
//  - wave grid 1x4: each wave owns 128(i) x 64(o); B fragments loaded
//    direct-to-register from fragment-major depb (redundancy-free, coalesced,
//    L2-resident), prefetched one full iteration ahead (bfA/bfB, unroll-2).
//  - A (head*U -> bf16) staged in LDS, double-buffered 2x8KB, XOR-swizzled
//    ([5:4]^=kgrp on ushort offsets) so both ds_write and ds_read are
//    conflict-free.
//  - raw s_barrier + lgkmcnt(0) asm only (one barrier per K-step); all global
//    loads get compiler-counted vmcnt waits and stay in flight across
//    barriers.

#define B_ 16
#define S_ 256
#define D_ 768
#define L_ 32
#define KQ_ (D_ / 8)  // 96 groups of 8 d's
#define NT_ 24        // K-tiles of 32

typedef unsigned short ushort_t;
typedef __attribute__((ext_vector_type(4))) float f32x4;
typedef __attribute__((ext_vector_type(8))) short s16x8;

// round-half-up fp32->bf16 pair pack; f0 -> low half, f1 -> high half
__device__ __forceinline__ unsigned int pack_bf16(float f0, float f1) {
  unsigned int u0 = __builtin_bit_cast(unsigned int, f0) + 0x8000u;
  unsigned int u1 = __builtin_bit_cast(unsigned int, f1) + 0x8000u;
  return __builtin_amdgcn_perm(u1, u0, 0x07060302);
}

// ---------------------------------------------------------------------------
// Prep: one wave per 4 rows. Lane owns 12 d's in registers. t2 dots via
// per-lane FMA + butterfly shuffle reduce. dep waves also emit bf16 depb in
// fragment-major layout depb[b][d>>3][col][d&7].
// grid = 512 blocks x 256 thr = 2048 waves = B*S*2/4 rows.
// ---------------------------------------------------------------------------
__global__ __launch_bounds__(256) void prep_kernel(
    const float* __restrict__ head, const float* __restrict__ dep,
    const float* __restrict__ labelW, ushort_t* __restrict__ depb,
    float* __restrict__ t2h, float* __restrict__ t2d) {
  const int wave = threadIdx.x >> 6;
  const int lane = threadIdx.x & 63;
  const int g = blockIdx.x * 4 + wave;  // 0..2047
  const int sel = g >> 10;              // 0=head, 1=dep
  const int idx = g & 1023;
  const int b = idx >> 6;
  const int row0 = (idx & 63) * 4;
  const float* src = sel ? dep : head;
  float* t2x = sel ? t2d : t2h;
  const int d0 = lane * 12;

  float h[4][12];
  const float* rp = src + ((size_t)(b * S_ + row0)) * D_ + d0;
#pragma unroll
  for (int r = 0; r < 4; ++r) {
    float4 v0 = *(const float4*)(rp + (size_t)r * D_);
    float4 v1 = *(const float4*)(rp + (size_t)r * D_ + 4);
    float4 v2 = *(const float4*)(rp + (size_t)r * D_ + 8);
    h[r][0] = v0.x; h[r][1] = v0.y; h[r][2] = v0.z; h[r][3] = v0.w;
    h[r][4] = v1.x; h[r][5] = v1.y; h[r][6] = v1.z; h[r][7] = v1.w;
    h[r][8] = v2.x; h[r][9] = v2.y; h[r][10] = v2.z; h[r][11] = v2.w;
  }
  if (sel) {
    // fragment-major: ushort off = ((b*96 + (d>>3))*256 + col)*8 + (d&7)
    const size_t bb = (size_t)b * (KQ_ * S_ * 8);
    const int m = lane >> 1;  // d0 = 24m (even lane) or 24m+12 (odd lane)
#pragma unroll
    for (int r = 0; r < 4; ++r) {
      const int col = row0 + r;
      unsigned int q0 = pack_bf16(h[r][0], h[r][1]);
      unsigned int q1 = pack_bf16(h[r][2], h[r][3]);
      unsigned int q2 = pack_bf16(h[r][4], h[r][5]);
      unsigned int q3 = pack_bf16(h[r][6], h[r][7]);
      unsigned int q4 = pack_bf16(h[r][8], h[r][9]);
      unsigned int q5 = pack_bf16(h[r][10], h[r][11]);
      if ((lane & 1) == 0) {
        uint4 a = {q0, q1, q2, q3};  // d0..d7 @ kq=3m
        uint2 c = {q4, q5};          // d8..d11 @ kq=3m+1, dlow 0..3
        *(uint4*)(depb + bb + ((size_t)(3 * m) * S_ + col) * 8) = a;
        *(uint2*)(depb + bb + ((size_t)(3 * m + 1) * S_ + col) * 8) = c;
      } else {
        uint2 c = {q0, q1};          // d0..d3 @ kq=3m+1, dlow 4..7
        uint4 a = {q2, q3, q4, q5};  // d4..d11 @ kq=3m+2
        *(uint2*)(depb + bb + ((size_t)(3 * m + 1) * S_ + col) * 8 + 4) = c;
        *(uint4*)(depb + bb + ((size_t)(3 * m + 2) * S_ + col) * 8) = a;
      }
    }
  }
  const float* wbase = labelW + sel * D_ + d0;
  for (int l = 0; l < L_; ++l) {
    const float* wp = wbase + (size_t)l * (2 * D_);
    float4 w0 = *(const float4*)(wp);
    float4 w1 = *(const float4*)(wp + 4);
    float4 w2 = *(const float4*)(wp + 8);
    float w[12] = {w0.x, w0.y, w0.z, w0.w, w1.x, w1.y, w1.z, w1.w,
                   w2.x, w2.y, w2.z, w2.w};
    float p0 = 0.f, p1 = 0.f, p2 = 0.f, p3 = 0.f;
#pragma unroll
    for (int j = 0; j < 12; ++j) {
      p0 += h[0][j] * w[j];
      p1 += h[1][j] * w[j];
      p2 += h[2][j] * w[j];
      p3 += h[3][j] * w[j];
    }
#pragma unroll
    for (int off = 32; off >= 1; off >>= 1) {
      p0 += __shfl_xor(p0, off);
      p1 += __shfl_xor(p1, off);
      p2 += __shfl_xor(p2, off);
      p3 += __shfl_xor(p3, off);
    }
    if (lane < 4) {
      float v = lane == 0 ? p0 : lane == 1 ? p1 : lane == 2 ? p2 : p3;
      t2x[((size_t)(b * L_ + l)) * S_ + row0 + lane] = v;
    }
  }
}

// ---------------------------------------------------------------------------
// Main: block = (b, l, i-half). Tile 128(i) x 256(o), 4 waves of 128x64.
// grid = B*L*2 = 1024 blocks, 256 threads.
// ---------------------------------------------------------------------------

// XOR-swizzle on ushort offsets within an 8KB A buffer: kgrp (bits 11:10)
// into bits 5:4. Bijective; makes A ds_write (kg varies per lane) and
// ds_read (kg fixed per 16-lane group) both uniform 2/bank.
#define SWZ(o) ((o) ^ ((((o) >> 10) & 3) << 4))

__global__ __launch_bounds__(256, 2) void main_kernel(
    const float* __restrict__ head, const ushort_t* __restrict__ depb,
    const float* __restrict__ U, const float* __restrict__ bias,
    const float* __restrict__ t2h, const float* __restrict__ t2d,
    float* __restrict__ out) {
  // A fragment-major [buf][kgrp(4)][row(128)][8] bf16, XOR-swizzled
  __shared__ __attribute__((aligned(16))) ushort_t As[2 * 128 * 32];  // 16 KB
  __shared__ float T2[384];  // [0:128]=t2h tile rows, [128:384]=t2d all cols

  // XCD-bijective swizzle: grid 1024 = 8 XCDs x 128 contiguous blocks (2 b's)
  const int hw = blockIdx.x;
  const int bid = ((hw & 7) << 7) | (hw >> 3);
  const int ic = bid & 1;
  const int bl = bid >> 1;
  const int l = bl & (L_ - 1);
  const int b = bl >> 5;
  const int ti = ic * 128;
  const int t = threadIdx.x;
  const int lane = t & 63;
  const int wave = t >> 6;

  for (int i = t; i < 384; i += 256)
    T2[i] = (i < 128) ? t2h[((size_t)(b * L_ + l)) * S_ + ti + i]
                      : t2d[((size_t)(b * L_ + l)) * S_ + (i - 128)];
  const float bv = bias[l];

  // A staging decomposition: thread t stages rows (t>>2, t>>2+64), kgrp t&3
  const int row0 = t >> 2;
  const int kg = t & 3;
  const float* hp0 = head + ((size_t)(b * S_ + ti + row0)) * D_ + kg * 8;
  const float* hp1 = hp0 + (size_t)64 * D_;
  const float* Up = U + (size_t)l * D_ + kg * 8;
  const int awo0s = SWZ((kg * 128 + row0) * 8);
  const int awo1s = awo0s + 512;  // +64 rows; doesn't touch swizzled bits

  // A frag reads: rows rt*16+(lane&15), kgrp=lane>>4 -> 256B/16-lane group
  const int aros = SWZ(((lane >> 4) * 128 + (lane & 15)) * 8);

  // B direct-from-global: wave owns cols [wave*64, wave*64+64)
  const ushort_t* dfb = depb + (size_t)b * (KQ_ * S_ * 8) +
                        ((size_t)((lane >> 4) * 256 + wave * 64 + (lane & 15))) * 8;

  f32x4 acc[8][4];
#pragma unroll
  for (int i = 0; i < 8; ++i)
#pragma unroll
    for (int j = 0; j < 4; ++j) acc[i][j] = {0.f, 0.f, 0.f, 0.f};

  s16x8 bfA[4], bfB[4];

  // prologue: stage A(0) into buf 0; load bfA <- B tile 0
  {
    float4 h0 = *(const float4*)(hp0);
    float4 h1 = *(const float4*)(hp0 + 4);
    float4 h2 = *(const float4*)(hp1);
    float4 h3 = *(const float4*)(hp1 + 4);
    float4 u0 = *(const float4*)(Up);
    float4 u1 = *(const float4*)(Up + 4);
    uint4 w0, w1;
    w0.x = pack_bf16(h0.x * u0.x, h0.y * u0.y);
    w0.y = pack_bf16(h0.z * u0.z, h0.w * u0.w);
    w0.z = pack_bf16(h1.x * u1.x, h1.y * u1.y);
    w0.w = pack_bf16(h1.z * u1.z, h1.w * u1.w);
    w1.x = pack_bf16(h2.x * u0.x, h2.y * u0.y);
    w1.y = pack_bf16(h2.z * u0.z, h2.w * u0.w);
    w1.z = pack_bf16(h3.x * u1.x, h3.y * u1.y);
    w1.w = pack_bf16(h3.z * u1.z, h3.w * u1.w);
    *(uint4*)(As + awo0s) = w0;
    *(uint4*)(As + awo1s) = w1;
#pragma unroll
    for (int ct = 0; ct < 4; ++ct)
      bfA[ct] = *(const s16x8*)(dfb + ct * 128);
  }
  asm volatile("s_waitcnt lgkmcnt(0)" ::: "memory");
  __builtin_amdgcn_s_barrier();
  __builtin_amdgcn_sched_barrier(0);

  // Per iteration (tile tcur, A in buf PB): issue next tile's h/u + B-frag
  // loads (compiler-counted vmcnt; in flight across the barrier), 8 ds_read
  // A frags, 32 MFMA, pack+ds_write A(t+1) into buf PB^1, lgkm-only barrier.
#define ITER(PB, BFC, BFN, tcur)                                              \
  {                                                                           \
    int tn = (tcur) + 1;                                                      \
    if (tn == NT_) tn = 0; /* wrapped dummy prefetch keeps code uniform */    \
    const float* hA = hp0 + tn * 32;                                          \
    const float* hB = hp1 + tn * 32;                                          \
    const float* uA = Up + tn * 32;                                           \
    float4 h0 = *(const float4*)(hA);                                         \
    float4 h1 = *(const float4*)(hA + 4);                                     \
    float4 h2 = *(const float4*)(hB);                                         \
    float4 h3 = *(const float4*)(hB + 4);                                     \
    float4 u0 = *(const float4*)(uA);                                         \
    float4 u1 = *(const float4*)(uA + 4);                                     \
    const ushort_t* dfn = dfb + (size_t)tn * 8192;                            \
    _Pragma("unroll") for (int ct = 0; ct < 4; ++ct)                          \
        BFN[ct] = *(const s16x8*)(dfn + ct * 128);                            \
    __builtin_amdgcn_sched_barrier(0); /* pin load-issue cluster here */      \
    s16x8 af[8];                                                              \
    _Pragma("unroll") for (int rt = 0; rt < 8; ++rt)                          \
        af[rt] = *(const s16x8*)(As + (PB)*4096 + aros + rt * 128);           \
    __builtin_amdgcn_s_setprio(1);                                            \
    _Pragma("unroll") for (int rt = 0; rt < 8; ++rt)                          \
      _Pragma("unroll") for (int ct = 0; ct < 4; ++ct)                        \
          acc[rt][ct] = __builtin_amdgcn_mfma_f32_16x16x32_bf16(              \
              af[rt], BFC[ct], acc[rt][ct], 0, 0, 0);                         \
    __builtin_amdgcn_s_setprio(0);                                            \
    uint4 w0, w1;                                                             \
    w0.x = pack_bf16(h0.x * u0.x, h0.y * u0.y);                               \
    w0.y = pack_bf16(h0.z * u0.z, h0.w * u0.w);                               \
    w0.z = pack_bf16(h1.x * u1.x, h1.y * u1.y);                               \
    w0.w = pack_bf16(h1.z * u1.z, h1.w * u1.w);                               \
    w1.x = pack_bf16(h2.x * u0.x, h2.y * u0.y);                               \
    w1.y = pack_bf16(h2.z * u0.z, h2.w * u0.w);                               \
    w1.z = pack_bf16(h3.x * u1.x, h3.y * u1.y);                               \
    w1.w = pack_bf16(h3.z * u1.z, h3.w * u1.w);                               \
    ushort_t* aw = As + ((PB) ^ 1) * 4096;                                    \
    *(uint4*)(aw + awo0s) = w0;                                               \
    *(uint4*)(aw + awo1s) = w1;                                               \
    asm volatile("s_waitcnt lgkmcnt(0)" ::: "memory");                        \
    __builtin_amdgcn_s_barrier();                                             \
    __builtin_amdgcn_sched_barrier(0);                                        \
  }

  for (int tt = 0; tt < NT_; tt += 2) {
    ITER(0, bfA, bfB, tt);
    ITER(1, bfB, bfA, tt + 1);
  }
#undef ITER

  // epilogue: C/D layout col=lane&15, row=(lane>>4)*4+reg
  const int colg = lane & 15;
  const int rgrp = lane >> 4;
  float* ob = out + (((size_t)(b * L_ + l)) * S_ + ti) * S_;
#pragma unroll
  for (int rt = 0; rt < 8; ++rt) {
    const int r0 = rt * 16 + rgrp * 4;
#pragma unroll
    for (int ct = 0; ct < 4; ++ct) {
      const int c = wave * 64 + ct * 16 + colg;
      const float addc = T2[128 + c] + bv;
      float* p = ob + (size_t)r0 * S_ + c;
#pragma unroll
      for (int r = 0; r < 4; ++r)
        p[(size_t)r * S_] = acc[rt][ct][r] + T2[r0 + r] + addc;
    }
  }
}

extern "C" void kernel_launch(void* const* d_in, const int* in_sizes, int n_in,
                              void* d_out, int out_size, void* d_ws, size_t ws_size,
                              hipStream_t stream) {
  const float* head = (const float*)d_in[0];
  const float* dep = (const float*)d_in[1];
  const float* U = (const float*)d_in[2];
  const float* W = (const float*)d_in[3];
  const float* bias = (const float*)d_in[4];
  float* out = (float*)d_out;

  ushort_t* depb = (ushort_t*)d_ws;                              // 6,291,456 B
  float* t2h = (float*)((char*)d_ws + (size_t)B_ * S_ * D_ * 2);
  float* t2d = t2h + (size_t)B_ * L_ * S_;                       // 524,288 B each

  prep_kernel<<<512, 256, 0, stream>>>(head, dep, W, depb, t2h, t2d);
  main_kernel<<<B_ * L_ * 2, 256, 0, stream>>>(head, depb, U, bias, t2h, t2d, out);
}

// Round 4
// 213.530 us; speedup vs baseline: 1.2549x; 1.0748x over previous
//
#include <hip/hip_runtime.h>
#include <hip/hip_bf16.h>
#include <stdint.h>

// out[b,l,i,o] = sum_d head[b,i,d]*U[l,d]*dep[b,o,d] + t2h[b,l,i] + t2d[b,l,o] + b[l]
// B=16, S=256, D=768, L=32. out (16,32,256,256) fp32.
//
// R6: prep rewritten with packed transpose-butterfly reduce (63 shuffles per
// 64 outputs instead of 6 per output: 768 -> 126 DS ops/wave). Summation tree
// is bit-identical to the old per-output allreduce, so t2 values are exact.
// main_kernel byte-identical to R5 (clean A/B on the total-minus-main gap).

#define B_ 16
#define S_ 256
#define D_ 768
#define L_ 32
#define KQ_ (D_ / 8)  // 96 groups of 8 d's
#define NT_ 24        // K-tiles of 32

typedef unsigned short ushort_t;
typedef __attribute__((ext_vector_type(4))) float f32x4;
typedef __attribute__((ext_vector_type(8))) short s16x8;

// round-half-up fp32->bf16 pair pack; f0 -> low half, f1 -> high half
__device__ __forceinline__ unsigned int pack_bf16(float f0, float f1) {
  unsigned int u0 = __builtin_bit_cast(unsigned int, f0) + 0x8000u;
  unsigned int u1 = __builtin_bit_cast(unsigned int, f1) + 0x8000u;
  return __builtin_amdgcn_perm(u1, u0, 0x07060302);
}

// ---------------------------------------------------------------------------
// Prep: one wave per 4 rows. Lane owns 12 d's in registers. t2 dots: per-lane
// FMA partials for 16 labels x 4 rows, then ONE packed transpose-butterfly
// (63 shuffles) delivers output j = l*4 + r to lane j. Two label-chunks.
// dep waves also emit bf16 depb in fragment-major layout
// depb[b][d>>3][col][d&7]. grid = 512 x 256 = 2048 waves = B*S*2/4 rows.
// ---------------------------------------------------------------------------
__global__ __launch_bounds__(256) void prep_kernel(
    const float* __restrict__ head, const float* __restrict__ dep,
    const float* __restrict__ labelW, ushort_t* __restrict__ depb,
    float* __restrict__ t2h, float* __restrict__ t2d) {
  const int wave = threadIdx.x >> 6;
  const int lane = threadIdx.x & 63;
  const int g = blockIdx.x * 4 + wave;  // 0..2047
  const int sel = g >> 10;              // 0=head, 1=dep
  const int idx = g & 1023;
  const int b = idx >> 6;
  const int row0 = (idx & 63) * 4;
  const float* src = sel ? dep : head;
  float* t2x = sel ? t2d : t2h;
  const int d0 = lane * 12;

  float h[4][12];
  const float* rp = src + ((size_t)(b * S_ + row0)) * D_ + d0;
#pragma unroll
  for (int r = 0; r < 4; ++r) {
    float4 v0 = *(const float4*)(rp + (size_t)r * D_);
    float4 v1 = *(const float4*)(rp + (size_t)r * D_ + 4);
    float4 v2 = *(const float4*)(rp + (size_t)r * D_ + 8);
    h[r][0] = v0.x; h[r][1] = v0.y; h[r][2] = v0.z; h[r][3] = v0.w;
    h[r][4] = v1.x; h[r][5] = v1.y; h[r][6] = v1.z; h[r][7] = v1.w;
    h[r][8] = v2.x; h[r][9] = v2.y; h[r][10] = v2.z; h[r][11] = v2.w;
  }
  if (sel) {
    // fragment-major: ushort off = ((b*96 + (d>>3))*256 + col)*8 + (d&7)
    const size_t bb = (size_t)b * (KQ_ * S_ * 8);
    const int m = lane >> 1;  // d0 = 24m (even lane) or 24m+12 (odd lane)
#pragma unroll
    for (int r = 0; r < 4; ++r) {
      const int col = row0 + r;
      unsigned int q0 = pack_bf16(h[r][0], h[r][1]);
      unsigned int q1 = pack_bf16(h[r][2], h[r][3]);
      unsigned int q2 = pack_bf16(h[r][4], h[r][5]);
      unsigned int q3 = pack_bf16(h[r][6], h[r][7]);
      unsigned int q4 = pack_bf16(h[r][8], h[r][9]);
      unsigned int q5 = pack_bf16(h[r][10], h[r][11]);
      if ((lane & 1) == 0) {
        uint4 a = {q0, q1, q2, q3};  // d0..d7 @ kq=3m
        uint2 c = {q4, q5};          // d8..d11 @ kq=3m+1, dlow 0..3
        *(uint4*)(depb + bb + ((size_t)(3 * m) * S_ + col) * 8) = a;
        *(uint2*)(depb + bb + ((size_t)(3 * m + 1) * S_ + col) * 8) = c;
      } else {
        uint2 c = {q0, q1};          // d0..d3 @ kq=3m+1, dlow 4..7
        uint4 a = {q2, q3, q4, q5};  // d4..d11 @ kq=3m+2
        *(uint2*)(depb + bb + ((size_t)(3 * m + 1) * S_ + col) * 8 + 4) = c;
        *(uint4*)(depb + bb + ((size_t)(3 * m + 2) * S_ + col) * 8) = a;
      }
    }
  }
  const float* wbase = labelW + sel * D_ + d0;
  // two chunks of 16 labels; v[j] = partial for output j = lq*4 + r
  for (int c = 0; c < 2; ++c) {
    float v[64];
#pragma unroll
    for (int j = 0; j < 64; ++j) v[j] = 0.f;
    const float* wc = wbase + (size_t)(c * 16) * (2 * D_);
#pragma unroll
    for (int lq = 0; lq < 16; ++lq) {
      const float* wp = wc + (size_t)lq * (2 * D_);
      float4 w0 = *(const float4*)(wp);
      float4 w1 = *(const float4*)(wp + 4);
      float4 w2 = *(const float4*)(wp + 8);
      float w[12] = {w0.x, w0.y, w0.z, w0.w, w1.x, w1.y, w1.z, w1.w,
                     w2.x, w2.y, w2.z, w2.w};
#pragma unroll
      for (int j = 0; j < 12; ++j) {
        v[lq * 4 + 0] += h[0][j] * w[j];
        v[lq * 4 + 1] += h[1][j] * w[j];
        v[lq * 4 + 2] += h[2][j] * w[j];
        v[lq * 4 + 3] += h[3][j] * w[j];
      }
    }
    // packed transpose-butterfly: at step `off`, exchange the half of the
    // live values whose index-bit `off` mismatches the lane's bit. After all
    // 6 steps, v[0] on lane L is the full 64-lane sum for output L. Combine
    // order (own + partner, high bit first) matches the old allreduce
    // bit-for-bit.
#pragma unroll
    for (int off = 32; off >= 1; off >>= 1) {
      const bool hi = (lane & off) != 0;
#pragma unroll
      for (int k = 0; k < 64; ++k) {
        if (k >= off) continue;  // live window is [0, off)
        float send = hi ? v[k] : v[k + off];
        float keep = hi ? v[k + off] : v[k];
        v[k] = keep + __shfl_xor(send, off);
      }
    }
    t2x[((size_t)(b * L_ + c * 16 + (lane >> 2))) * S_ + row0 + (lane & 3)] =
        v[0];
  }
}

// ---------------------------------------------------------------------------
// Main: block = (b, l, i-half). Tile 128(i) x 256(o), 4 waves of 128x64.
// grid = B*L*2 = 1024 blocks, 256 threads.  (byte-identical to R5)
// ---------------------------------------------------------------------------

// XOR-swizzle on ushort offsets within an 8KB A buffer: kgrp (bits 11:10)
// into bits 5:4. Bijective; makes A ds_write (kg varies per lane) and
// ds_read (kg fixed per 16-lane group) both uniform 2/bank.
#define SWZ(o) ((o) ^ ((((o) >> 10) & 3) << 4))

__global__ __launch_bounds__(256, 2) void main_kernel(
    const float* __restrict__ head, const ushort_t* __restrict__ depb,
    const float* __restrict__ U, const float* __restrict__ bias,
    const float* __restrict__ t2h, const float* __restrict__ t2d,
    float* __restrict__ out) {
  // A fragment-major [buf][kgrp(4)][row(128)][8] bf16, XOR-swizzled
  __shared__ __attribute__((aligned(16))) ushort_t As[2 * 128 * 32];  // 16 KB
  __shared__ float T2[384];  // [0:128]=t2h tile rows, [128:384]=t2d all cols

  // XCD-bijective swizzle: grid 1024 = 8 XCDs x 128 contiguous blocks (2 b's)
  const int hw = blockIdx.x;
  const int bid = ((hw & 7) << 7) | (hw >> 3);
  const int ic = bid & 1;
  const int bl = bid >> 1;
  const int l = bl & (L_ - 1);
  const int b = bl >> 5;
  const int ti = ic * 128;
  const int t = threadIdx.x;
  const int lane = t & 63;
  const int wave = t >> 6;

  for (int i = t; i < 384; i += 256)
    T2[i] = (i < 128) ? t2h[((size_t)(b * L_ + l)) * S_ + ti + i]
                      : t2d[((size_t)(b * L_ + l)) * S_ + (i - 128)];
  const float bv = bias[l];

  // A staging decomposition: thread t stages rows (t>>2, t>>2+64), kgrp t&3
  const int row0 = t >> 2;
  const int kg = t & 3;
  const float* hp0 = head + ((size_t)(b * S_ + ti + row0)) * D_ + kg * 8;
  const float* hp1 = hp0 + (size_t)64 * D_;
  const float* Up = U + (size_t)l * D_ + kg * 8;
  const int awo0s = SWZ((kg * 128 + row0) * 8);
  const int awo1s = awo0s + 512;  // +64 rows; doesn't touch swizzled bits

  // A frag reads: rows rt*16+(lane&15), kgrp=lane>>4 -> 256B/16-lane group
  const int aros = SWZ(((lane >> 4) * 128 + (lane & 15)) * 8);

  // B direct-from-global: wave owns cols [wave*64, wave*64+64)
  const ushort_t* dfb = depb + (size_t)b * (KQ_ * S_ * 8) +
                        ((size_t)((lane >> 4) * 256 + wave * 64 + (lane & 15))) * 8;

  f32x4 acc[8][4];
#pragma unroll
  for (int i = 0; i < 8; ++i)
#pragma unroll
    for (int j = 0; j < 4; ++j) acc[i][j] = {0.f, 0.f, 0.f, 0.f};

  s16x8 bfA[4], bfB[4];

  // prologue: stage A(0) into buf 0; load bfA <- B tile 0
  {
    float4 h0 = *(const float4*)(hp0);
    float4 h1 = *(const float4*)(hp0 + 4);
    float4 h2 = *(const float4*)(hp1);
    float4 h3 = *(const float4*)(hp1 + 4);
    float4 u0 = *(const float4*)(Up);
    float4 u1 = *(const float4*)(Up + 4);
    uint4 w0, w1;
    w0.x = pack_bf16(h0.x * u0.x, h0.y * u0.y);
    w0.y = pack_bf16(h0.z * u0.z, h0.w * u0.w);
    w0.z = pack_bf16(h1.x * u1.x, h1.y * u1.y);
    w0.w = pack_bf16(h1.z * u1.z, h1.w * u1.w);
    w1.x = pack_bf16(h2.x * u0.x, h2.y * u0.y);
    w1.y = pack_bf16(h2.z * u0.z, h2.w * u0.w);
    w1.z = pack_bf16(h3.x * u1.x, h3.y * u1.y);
    w1.w = pack_bf16(h3.z * u1.z, h3.w * u1.w);
    *(uint4*)(As + awo0s) = w0;
    *(uint4*)(As + awo1s) = w1;
#pragma unroll
    for (int ct = 0; ct < 4; ++ct)
      bfA[ct] = *(const s16x8*)(dfb + ct * 128);
  }
  asm volatile("s_waitcnt lgkmcnt(0)" ::: "memory");
  __builtin_amdgcn_s_barrier();
  __builtin_amdgcn_sched_barrier(0);

  // Per iteration (tile tcur, A in buf PB): issue next tile's h/u + B-frag
  // loads (compiler-counted vmcnt; in flight across the barrier), 8 ds_read
  // A frags, 32 MFMA, pack+ds_write A(t+1) into buf PB^1, lgkm-only barrier.
#define ITER(PB, BFC, BFN, tcur)                                              \
  {                                                                           \
    int tn = (tcur) + 1;                                                      \
    if (tn == NT_) tn = 0; /* wrapped dummy prefetch keeps code uniform */    \
    const float* hA = hp0 + tn * 32;                                          \
    const float* hB = hp1 + tn * 32;                                          \
    const float* uA = Up + tn * 32;                                           \
    float4 h0 = *(const float4*)(hA);                                         \
    float4 h1 = *(const float4*)(hA + 4);                                     \
    float4 h2 = *(const float4*)(hB);                                         \
    float4 h3 = *(const float4*)(hB + 4);                                     \
    float4 u0 = *(const float4*)(uA);                                         \
    float4 u1 = *(const float4*)(uA + 4);                                     \
    const ushort_t* dfn = dfb + (size_t)tn * 8192;                            \
    _Pragma("unroll") for (int ct = 0; ct < 4; ++ct)                          \
        BFN[ct] = *(const s16x8*)(dfn + ct * 128);                            \
    __builtin_amdgcn_sched_barrier(0); /* pin load-issue cluster here */      \
    s16x8 af[8];                                                              \
    _Pragma("unroll") for (int rt = 0; rt < 8; ++rt)                          \
        af[rt] = *(const s16x8*)(As + (PB)*4096 + aros + rt * 128);           \
    __builtin_amdgcn_s_setprio(1);                                            \
    _Pragma("unroll") for (int rt = 0; rt < 8; ++rt)                          \
      _Pragma("unroll") for (int ct = 0; ct < 4; ++ct)                        \
          acc[rt][ct] = __builtin_amdgcn_mfma_f32_16x16x32_bf16(              \
              af[rt], BFC[ct], acc[rt][ct], 0, 0, 0);                         \
    __builtin_amdgcn_s_setprio(0);                                            \
    uint4 w0, w1;                                                             \
    w0.x = pack_bf16(h0.x * u0.x, h0.y * u0.y);                               \
    w0.y = pack_bf16(h0.z * u0.z, h0.w * u0.w);                               \
    w0.z = pack_bf16(h1.x * u1.x, h1.y * u1.y);                               \
    w0.w = pack_bf16(h1.z * u1.z, h1.w * u1.w);                               \
    w1.x = pack_bf16(h2.x * u0.x, h2.y * u0.y);                               \
    w1.y = pack_bf16(h2.z * u0.z, h2.w * u0.w);                               \
    w1.z = pack_bf16(h3.x * u1.x, h3.y * u1.y);                               \
    w1.w = pack_bf16(h3.z * u1.z, h3.w * u1.w);                               \
    ushort_t* aw = As + ((PB) ^ 1) * 4096;                                    \
    *(uint4*)(aw + awo0s) = w0;                                               \
    *(uint4*)(aw + awo1s) = w1;                                               \
    asm volatile("s_waitcnt lgkmcnt(0)" ::: "memory");                        \
    __builtin_amdgcn_s_barrier();                                             \
    __builtin_amdgcn_sched_barrier(0);                                        \
  }

  for (int tt = 0; tt < NT_; tt += 2) {
    ITER(0, bfA, bfB, tt);
    ITER(1, bfB, bfA, tt + 1);
  }
#undef ITER

  // epilogue: C/D layout col=lane&15, row=(lane>>4)*4+reg
  const int colg = lane & 15;
  const int rgrp = lane >> 4;
  float* ob = out + (((size_t)(b * L_ + l)) * S_ + ti) * S_;
#pragma unroll
  for (int rt = 0; rt < 8; ++rt) {
    const int r0 = rt * 16 + rgrp * 4;
#pragma unroll
    for (int ct = 0; ct < 4; ++ct) {
      const int c = wave * 64 + ct * 16 + colg;
      const float addc = T2[128 + c] + bv;
      float* p = ob + (size_t)r0 * S_ + c;
#pragma unroll
      for (int r = 0; r < 4; ++r)
        p[(size_t)r * S_] = acc[rt][ct][r] + T2[r0 + r] + addc;
    }
  }
}

extern "C" void kernel_launch(void* const* d_in, const int* in_sizes, int n_in,
                              void* d_out, int out_size, void* d_ws, size_t ws_size,
                              hipStream_t stream) {
  const float* head = (const float*)d_in[0];
  const float* dep = (const float*)d_in[1];
  const float* U = (const float*)d_in[2];
  const float* W = (const float*)d_in[3];
  const float* bias = (const float*)d_in[4];
  float* out = (float*)d_out;

  ushort_t* depb = (ushort_t*)d_ws;                              // 6,291,456 B
  float* t2h = (float*)((char*)d_ws + (size_t)B_ * S_ * D_ * 2);
  float* t2d = t2h + (size_t)B_ * L_ * S_;                       // 524,288 B each

  prep_kernel<<<512, 256, 0, stream>>>(head, dep, W, depb, t2h, t2d);
  main_kernel<<<B_ * L_ * 2, 256, 0, stream>>>(head, depb, U, bias, t2h, t2d, out);
}